// Round 2
// baseline (143.692 us; speedup 1.0000x reference)
//
#include <hip/hip_runtime.h>

// Problem constants (match reference setup_inputs)
#define BB   4
#define NN   100000
#define CC   128
#define RESO 128
#define PIX  (RESO * RESO)          // 16384 pixels per (b, plane)
#define PLANE_ELEMS (BB * PIX)      // 65536 floats per plane

// ---------------------------------------------------------------------------
// Kernel 1 (fused): channel-collapse with fc_w, final planes written directly.
//   ws[plane][b*PIX + idx] = sum_c fcw[c] * img[b][c][idx]
// Geometry: grid (256, 3), block 256 = 4 waves. Each block owns one chunk of
// 256 contiguous pixels (so b is block-uniform: 64 chunks per image). Wave w
// accumulates channels [w*32, (w+1)*32) with float4 loads (16 B/lane, the
// m13-verified streaming pattern); the 4 per-wave partials are reduced through
// 4 KB of LDS. 768 blocks = 3 blocks/CU = 12 waves/CU: same TLP as the
// previous slice-split version, but the collapse kernel and its 6.2 MB of
// ws round-trip traffic are gone.
// ---------------------------------------------------------------------------
__global__ __launch_bounds__(256) void reduce_planes_k(
    const float* __restrict__ cxz, const float* __restrict__ cxy,
    const float* __restrict__ cyz, const float* __restrict__ fcw,
    float* __restrict__ ws)
{
    const int t = threadIdx.x;
    const int w = t >> 6;            // wave 0..3  -> channel slice
    const int l = t & 63;            // lane
    const int plane = blockIdx.y;
    const int c0 = w * 32;

    __shared__ float wsm[CC];
    if (t < CC) wsm[t] = fcw[t];
    __syncthreads();

    const float* __restrict__ img = (plane == 0) ? cxz : (plane == 1) ? cxy : cyz;

    const int gp  = blockIdx.x * 256 + 4 * l;   // b*PIX + idx (chunk never straddles b)
    const int b   = blockIdx.x >> 6;            // 64 pixel-chunks per image
    const int idx = gp & (PIX - 1);

    const float4* __restrict__ base =
        reinterpret_cast<const float4*>(img + ((size_t)(b * CC + c0)) * PIX + idx);

    float4 acc = make_float4(0.f, 0.f, 0.f, 0.f);
#pragma unroll
    for (int c = 0; c < 32; ++c) {
        const float4 v  = base[c * (PIX / 4)];
        const float  wc = wsm[c0 + c];           // wave-uniform LDS broadcast
        acc.x = fmaf(wc, v.x, acc.x);
        acc.y = fmaf(wc, v.y, acc.y);
        acc.z = fmaf(wc, v.z, acc.z);
        acc.w = fmaf(wc, v.w, acc.w);
    }

    __shared__ float4 sp[4][64];
    sp[w][l] = acc;
    __syncthreads();

    if (t < 64) {
        const float4 a0 = sp[0][t], a1 = sp[1][t], a2 = sp[2][t], a3 = sp[3][t];
        float4 r;
        r.x = (a0.x + a1.x) + (a2.x + a3.x);
        r.y = (a0.y + a1.y) + (a2.y + a3.y);
        r.z = (a0.z + a1.z) + (a2.z + a3.z);
        r.w = (a0.w + a1.w) + (a2.w + a3.w);
        *reinterpret_cast<float4*>(
            ws + (size_t)plane * PLANE_ELEMS + blockIdx.x * 256 + 4 * t) = r;
    }
}

// ---------------------------------------------------------------------------
// Kernel 2: per-point bilinear sample of the 3 collapsed planes + linear head.
// After the [0, 1-1e-5] clip, x <= 127*(1-1e-5) -> x0 in [0,126], x1 = x0+1
// <= 127: no int clamps needed.
// ---------------------------------------------------------------------------
__device__ __forceinline__ float bilin(const float* __restrict__ pb,
                                       float a, float bc)
{
    const float INV = 1.0f / (1.0f + 0.1f + 1e-5f);   // 1/1.10001
    const float HI  = 1.0f - 1e-5f;

    const float u = fminf(fmaxf(fmaf(a,  INV, 0.5f), 0.0f), HI);
    const float v = fminf(fmaxf(fmaf(bc, INV, 0.5f), 0.0f), HI);

    const float x = u * (float)(RESO - 1);
    const float y = v * (float)(RESO - 1);
    const float xf = floorf(x), yf = floorf(y);
    const float wx = x - xf,    wy = y - yf;
    const int   x0 = (int)xf,   y0 = (int)yf;

    const float* __restrict__ r0 = pb + y0 * RESO + x0;
    const float* __restrict__ r1 = r0 + RESO;
    const float v00 = r0[0], v01 = r0[1];
    const float v10 = r1[0], v11 = r1[1];

    const float top = fmaf(wx, v01 - v00, v00);
    const float bot = fmaf(wx, v11 - v10, v10);
    return fmaf(wy, bot - top, top);
}

__global__ __launch_bounds__(256) void sample_k(
    const float* __restrict__ p, const float* __restrict__ ws,
    const float* __restrict__ fcw, const float* __restrict__ fcb,
    float* __restrict__ out)
{
    const int b  = blockIdx.y;              // batch index: no integer division
    const int n0 = blockIdx.x * 256;

    // Stage this block's 256x3 point coords through LDS with coalesced
    // dword loads (stride-3 direct loads waste ~3x transactions).
    __shared__ float sp[256 * 3];
    {
        const int cnt = min(256, NN - n0) * 3;
        const float* __restrict__ pb = p + (size_t)3 * ((size_t)b * NN + n0);
        for (int j = threadIdx.x; j < cnt; j += 256) sp[j] = pb[j];
    }
    __syncthreads();

    const int n = n0 + threadIdx.x;
    if (n >= NN) return;

    const float p0 = sp[3 * threadIdx.x + 0];
    const float p1 = sp[3 * threadIdx.x + 1];
    const float p2 = sp[3 * threadIdx.x + 2];

    const float* __restrict__ wsf = ws + (size_t)b * PIX;

    float s = bilin(wsf + 0 * PLANE_ELEMS, p0, p2)    // c_xz: (u=p0, v=p2)
            + bilin(wsf + 1 * PLANE_ELEMS, p0, p1)    // c_xy: (u=p0, v=p1)
            + bilin(wsf + 2 * PLANE_ELEMS, p1, p2);   // c_yz: (u=p1, v=p2)

    s = fmaf(p0, fcw[CC + 0], s);
    s = fmaf(p1, fcw[CC + 1], s);
    s = fmaf(p2, fcw[CC + 2], s);
    s += fcb[0];

    out[(size_t)b * NN + n] = s;
}

// ---------------------------------------------------------------------------
extern "C" void kernel_launch(void* const* d_in, const int* in_sizes, int n_in,
                              void* d_out, int out_size, void* d_ws, size_t ws_size,
                              hipStream_t stream) {
    const float* p   = (const float*)d_in[0];
    const float* cxz = (const float*)d_in[1];
    const float* cxy = (const float*)d_in[2];
    const float* cyz = (const float*)d_in[3];
    const float* fcw = (const float*)d_in[4];
    const float* fcb = (const float*)d_in[5];
    float* out = (float*)d_out;
    float* ws  = (float*)d_ws;   // uses 3*PLANE_ELEMS*4 = 786 KB

    // 256 x 3 = 768 blocks: stream all 100.7 MB of plane data, write final
    // collapsed planes directly (no separate collapse pass).
    dim3 g1(PLANE_ELEMS / 256, 3);
    reduce_planes_k<<<g1, 256, 0, stream>>>(cxz, cxy, cyz, fcw, ws);

    // 391 x 4 blocks: bilinear sample + head.
    dim3 g3((NN + 255) / 256, BB);
    sample_k<<<g3, 256, 0, stream>>>(p, ws, fcw, fcb, out);
}